// Round 1
// baseline (357.033 us; speedup 1.0000x reference)
//
#include <hip/hip_runtime.h>

static constexpr float kEPS  = 1e-12f;
static constexpr float kLOW  = 0.02f;
static constexpr float kHIGH = 0.98f;

__device__ __forceinline__ float fast_sigmoid(float v) {
    return 1.0f / (1.0f + __expf(-v));
}

__global__ __launch_bounds__(256) void sinkhorn_mlp_kernel(
    const float* __restrict__ margins,
    const float* __restrict__ W1, const float* __restrict__ b1,
    const float* __restrict__ W2, const float* __restrict__ b2,
    const float* __restrict__ W3, const float* __restrict__ b3,
    const float* __restrict__ W4, const float* __restrict__ b4,
    float* __restrict__ out_mus, float* __restrict__ out_V, int B)
{
    const int tid = blockIdx.x * blockDim.x + threadIdx.x;
    if (tid >= B) return;

    // ---- load row (6 fp32, coalesced-ish: 24 B/lane contiguous per wave) ----
    const float* mp = margins + (size_t)tid * 6;
    float x[6];
#pragma unroll
    for (int j = 0; j < 6; ++j) x[j] = mp[j];

    // ---- layer 1: 6 -> 64, relu. Weights via scalar loads (uniform addr). ----
    float h1[64];
#pragma unroll
    for (int k = 0; k < 64; ++k) {
        float a = b1[k];
#pragma unroll
        for (int j = 0; j < 6; ++j) a = fmaf(x[j], W1[j * 64 + k], a);
        h1[k] = fmaxf(a, 0.0f);
    }

    // ---- layer 2: 64 -> 32, relu ----
    float h2[32];
#pragma unroll
    for (int k = 0; k < 32; ++k) {
        float a = b2[k];
#pragma unroll
        for (int j = 0; j < 64; ++j) a = fmaf(h1[j], W2[j * 32 + k], a);
        h2[k] = fmaxf(a, 0.0f);
    }

    // ---- layer 3: 32 -> 16, relu ----
    float h3[16];
#pragma unroll
    for (int k = 0; k < 16; ++k) {
        float a = b3[k];
#pragma unroll
        for (int j = 0; j < 32; ++j) a = fmaf(h2[j], W3[j * 16 + k], a);
        h3[k] = fmaxf(a, 0.0f);
    }

    // ---- layer 4: 16 -> 9 (no relu) ----
    float p[9];
#pragma unroll
    for (int k = 0; k < 9; ++k) {
        float a = b4[k];
#pragma unroll
        for (int j = 0; j < 16; ++j) a = fmaf(h3[j], W4[j * 9 + k], a);
        p[k] = a;
    }

    // ---- heads ----
    // tau: 3x3 of ones with top-left 2x2 = exp(p[0:4]) reshaped row-major
    float A00 = __expf(p[0]), A01 = __expf(p[1]);
    float A10 = __expf(p[2]), A11 = __expf(p[3]);
    float A02 = 1.0f, A12 = 1.0f, A20 = 1.0f, A21 = 1.0f, A22 = 1.0f;

    const float sh_m0 = kLOW + (kHIGH - kLOW) * fast_sigmoid(p[4]);
    const float sh_m1 = kLOW + (kHIGH - kLOW) * fast_sigmoid(p[5]);
    const float sh_f0 = kLOW + (kHIGH - kLOW) * fast_sigmoid(p[6]);
    const float sh_f1 = kLOW + (kHIGH - kLOW) * fast_sigmoid(p[7]);
    const float V = __expf(p[8]);

    const float M0 = x[0], M1 = x[1], M2 = x[2];
    const float F0 = x[3], F1 = x[4], F2 = x[5];

    // row margins r = M * shm0 (shm0 = [sh_m0, sh_m1, 1])
    const float r0 = M0 * sh_m0, r1 = M1 * sh_m1, r2 = M2;
    // col margins c = F * shf0
    const float c0 = F0 * sh_f0, c1 = F1 * sh_f1, c2 = F2;
    // unmatched masses
    const float mum0_0 = M0 * (1.0f - sh_m0), mum0_1 = M1 * (1.0f - sh_m1);
    const float mu0f_0 = F0 * (1.0f - sh_f0), mu0f_1 = F1 * (1.0f - sh_f1);

    // ---- Sinkhorn-Knopp, 10 iterations, fully in registers ----
#pragma unroll
    for (int it = 0; it < 10; ++it) {
        // row normalize: A *= r / (rowsum + EPS)
        float s0 = A00 + A01 + A02;
        float s1 = A10 + A11 + A12;
        float s2 = A20 + A21 + A22;
        float f0 = __fdividef(r0, s0 + kEPS);
        float f1 = __fdividef(r1, s1 + kEPS);
        float f2 = __fdividef(r2, s2 + kEPS);
        A00 *= f0; A01 *= f0; A02 *= f0;
        A10 *= f1; A11 *= f1; A12 *= f1;
        A20 *= f2; A21 *= f2; A22 *= f2;
        // col normalize: A *= c / (colsum + EPS)
        float t0 = A00 + A10 + A20;
        float t1 = A01 + A11 + A21;
        float t2 = A02 + A12 + A22;
        float g0 = __fdividef(c0, t0 + kEPS);
        float g1 = __fdividef(c1, t1 + kEPS);
        float g2 = __fdividef(c2, t2 + kEPS);
        A00 *= g0; A10 *= g0; A20 *= g0;
        A01 *= g1; A11 *= g1; A21 *= g1;
        A02 *= g2; A12 *= g2; A22 *= g2;
    }

    // ---- write mus (4x4) + V ----
    float4* o = (float4*)(out_mus + (size_t)tid * 16);
    o[0] = make_float4(A00, A01, A02, mum0_0);
    o[1] = make_float4(A10, A11, A12, mum0_1);
    o[2] = make_float4(A20, A21, A22, 0.0f);
    o[3] = make_float4(mu0f_0, mu0f_1, 0.0f, 0.0f);
    out_V[tid] = V;
}

extern "C" void kernel_launch(void* const* d_in, const int* in_sizes, int n_in,
                              void* d_out, int out_size, void* d_ws, size_t ws_size,
                              hipStream_t stream) {
    const float* margins = (const float*)d_in[0];
    const float* W1 = (const float*)d_in[1];
    const float* b1 = (const float*)d_in[2];
    const float* W2 = (const float*)d_in[3];
    const float* b2 = (const float*)d_in[4];
    const float* W3 = (const float*)d_in[5];
    const float* b3 = (const float*)d_in[6];
    const float* W4 = (const float*)d_in[7];
    const float* b4 = (const float*)d_in[8];

    const int B = in_sizes[0] / 6;
    float* out_mus = (float*)d_out;
    float* out_V   = out_mus + (size_t)B * 16;

    dim3 block(256);
    dim3 grid((B + 255) / 256);
    hipLaunchKernelGGL(sinkhorn_mlp_kernel, grid, block, 0, stream,
                       margins, W1, b1, W2, b2, W3, b3, W4, b4,
                       out_mus, out_V, B);
}

// Round 2
// 332.310 us; speedup vs baseline: 1.0744x; 1.0744x over previous
//
#include <hip/hip_runtime.h>

static constexpr float kEPS  = 1e-12f;
static constexpr float kLOW  = 0.02f;
static constexpr float kHIGH = 0.98f;

__device__ __forceinline__ float fast_sigmoid(float v) {
    return 1.0f / (1.0f + __expf(-v));
}

// __launch_bounds__(256, 2): 2 waves/EU min -> up to 256 VGPR/wave. Round 1
// showed VGPR_Count=32 with ~2.6x VALU bloat from v_accvgpr spill shuffling;
// peak live set here is ~60 fp32, so give the allocator room.
__global__ __launch_bounds__(256, 2) void sinkhorn_mlp_kernel(
    const float* __restrict__ margins,
    const float* __restrict__ W1, const float* __restrict__ b1,
    const float* __restrict__ W2, const float* __restrict__ b2,
    const float* __restrict__ W3, const float* __restrict__ b3,
    const float* __restrict__ W4, const float* __restrict__ b4,
    float* __restrict__ out_mus, float* __restrict__ out_V, int B)
{
    const int tid = blockIdx.x * blockDim.x + threadIdx.x;
    if (tid >= B) return;

    const float* mp = margins + (size_t)tid * 6;
    float x[6];
#pragma unroll
    for (int j = 0; j < 6; ++j) x[j] = mp[j];

    // ---- fused layer1+layer2: h1_j produced and consumed immediately ----
    // h2 accumulators live across; h1 never materialized as an array.
    float h2[32];
#pragma unroll
    for (int k = 0; k < 32; ++k) h2[k] = b2[k];

#pragma unroll 4
    for (int j = 0; j < 64; ++j) {
        float a = b1[j];
#pragma unroll
        for (int i = 0; i < 6; ++i) a = fmaf(x[i], W1[i * 64 + j], a);
        a = fmaxf(a, 0.0f);  // relu(h1_j)
#pragma unroll
        for (int k = 0; k < 32; ++k) h2[k] = fmaf(a, W2[j * 32 + k], h2[k]);
    }

    // ---- fused layer2-relu + layer3 ----
    float h3[16];
#pragma unroll
    for (int k = 0; k < 16; ++k) h3[k] = b3[k];

#pragma unroll 4
    for (int j = 0; j < 32; ++j) {
        float a = fmaxf(h2[j], 0.0f);
#pragma unroll
        for (int k = 0; k < 16; ++k) h3[k] = fmaf(a, W3[j * 16 + k], h3[k]);
    }

    // ---- fused layer3-relu + layer4 (no relu on output) ----
    float p[9];
#pragma unroll
    for (int k = 0; k < 9; ++k) p[k] = b4[k];

#pragma unroll 4
    for (int j = 0; j < 16; ++j) {
        float a = fmaxf(h3[j], 0.0f);
#pragma unroll
        for (int k = 0; k < 9; ++k) p[k] = fmaf(a, W4[j * 9 + k], p[k]);
    }

    // ---- heads ----
    float A00 = __expf(p[0]), A01 = __expf(p[1]);
    float A10 = __expf(p[2]), A11 = __expf(p[3]);
    float A02 = 1.0f, A12 = 1.0f, A20 = 1.0f, A21 = 1.0f, A22 = 1.0f;

    const float sh_m0 = kLOW + (kHIGH - kLOW) * fast_sigmoid(p[4]);
    const float sh_m1 = kLOW + (kHIGH - kLOW) * fast_sigmoid(p[5]);
    const float sh_f0 = kLOW + (kHIGH - kLOW) * fast_sigmoid(p[6]);
    const float sh_f1 = kLOW + (kHIGH - kLOW) * fast_sigmoid(p[7]);
    const float V = __expf(p[8]);

    const float M0 = x[0], M1 = x[1], M2 = x[2];
    const float F0 = x[3], F1 = x[4], F2 = x[5];

    const float r0 = M0 * sh_m0, r1 = M1 * sh_m1, r2 = M2;
    const float c0 = F0 * sh_f0, c1 = F1 * sh_f1, c2 = F2;
    const float mum0_0 = M0 * (1.0f - sh_m0), mum0_1 = M1 * (1.0f - sh_m1);
    const float mu0f_0 = F0 * (1.0f - sh_f0), mu0f_1 = F1 * (1.0f - sh_f1);

    // ---- Sinkhorn-Knopp, 10 iterations, all in registers ----
#pragma unroll
    for (int it = 0; it < 10; ++it) {
        float s0 = A00 + A01 + A02;
        float s1 = A10 + A11 + A12;
        float s2 = A20 + A21 + A22;
        float f0 = __fdividef(r0, s0 + kEPS);
        float f1 = __fdividef(r1, s1 + kEPS);
        float f2 = __fdividef(r2, s2 + kEPS);
        A00 *= f0; A01 *= f0; A02 *= f0;
        A10 *= f1; A11 *= f1; A12 *= f1;
        A20 *= f2; A21 *= f2; A22 *= f2;
        float t0 = A00 + A10 + A20;
        float t1 = A01 + A11 + A21;
        float t2 = A02 + A12 + A22;
        float g0 = __fdividef(c0, t0 + kEPS);
        float g1 = __fdividef(c1, t1 + kEPS);
        float g2 = __fdividef(c2, t2 + kEPS);
        A00 *= g0; A10 *= g0; A20 *= g0;
        A01 *= g1; A11 *= g1; A21 *= g1;
        A02 *= g2; A12 *= g2; A22 *= g2;
    }

    // ---- write mus (4x4, coalesced float4) + V ----
    float4* o = (float4*)(out_mus + (size_t)tid * 16);
    o[0] = make_float4(A00, A01, A02, mum0_0);
    o[1] = make_float4(A10, A11, A12, mum0_1);
    o[2] = make_float4(A20, A21, A22, 0.0f);
    o[3] = make_float4(mu0f_0, mu0f_1, 0.0f, 0.0f);
    out_V[tid] = V;
}

extern "C" void kernel_launch(void* const* d_in, const int* in_sizes, int n_in,
                              void* d_out, int out_size, void* d_ws, size_t ws_size,
                              hipStream_t stream) {
    const float* margins = (const float*)d_in[0];
    const float* W1 = (const float*)d_in[1];
    const float* b1 = (const float*)d_in[2];
    const float* W2 = (const float*)d_in[3];
    const float* b2 = (const float*)d_in[4];
    const float* W3 = (const float*)d_in[5];
    const float* b3 = (const float*)d_in[6];
    const float* W4 = (const float*)d_in[7];
    const float* b4 = (const float*)d_in[8];

    const int B = in_sizes[0] / 6;
    float* out_mus = (float*)d_out;
    float* out_V   = out_mus + (size_t)B * 16;

    dim3 block(256);
    dim3 grid((B + 255) / 256);
    hipLaunchKernelGGL(sinkhorn_mlp_kernel, grid, block, 0, stream,
                       margins, W1, b1, W2, b2, W3, b3, W4, b4,
                       out_mus, out_V, B);
}

// Round 3
// 250.690 us; speedup vs baseline: 1.4242x; 1.3256x over previous
//
#include <hip/hip_runtime.h>

typedef _Float16 f16x8 __attribute__((ext_vector_type(8)));
typedef float    f32x4 __attribute__((ext_vector_type(4)));

static constexpr float kEPS  = 1e-12f;
static constexpr float kLOW  = 0.02f;
static constexpr float kHIGH = 0.98f;

__device__ __forceinline__ float fast_sigmoid(float v) {
    return 1.0f / (1.0f + __expf(-v));
}

// Per-wave layout: 64 rows/wave, waves independent (no barriers).
// LDS slice per wave: 9216 B, reused: H1 (f16, 64 x stride 144B)
//   -> H2 (f16, 64 x stride 80B) -> H3 (f32, 64 x stride 80B).
// All A-fragments are pre-read to VGPRs before the aliasing writes.
__global__ __launch_bounds__(256, 2) void sinkhorn_mlp_mfma(
    const float* __restrict__ margins,
    const float* __restrict__ W1, const float* __restrict__ b1,
    const float* __restrict__ W2, const float* __restrict__ b2,
    const float* __restrict__ W3, const float* __restrict__ b3,
    const float* __restrict__ W4, const float* __restrict__ b4,
    float* __restrict__ out_mus, float* __restrict__ out_V, int B)
{
    __shared__ __align__(16) char smem_all[4 * 9216];
    const int lane = threadIdx.x & 63;
    const int wid  = threadIdx.x >> 6;
    char* smem = smem_all + wid * 9216;

    const int n16 = lane & 15;   // MFMA col / m index
    const int q   = lane >> 4;   // quad 0..3

    const int row  = blockIdx.x * 256 + wid * 64 + lane;
    const int rowC = row < B ? row : (B - 1);

    // ---- B-fragments (weights, wave-invariant) into VGPRs, f16 ----
    // B-frag layout (m92-verified pattern): lane(n=lane&15, quad q) holds
    // B[k = q*8+j][n], j ascending in memory order — same slot rule as A.
    f16x8 B2f[2][2];  // [kt][nt]  K=64 -> 2 k-tiles, N=32 -> 2 n-tiles
#pragma unroll
    for (int kt = 0; kt < 2; ++kt)
#pragma unroll
        for (int nt = 0; nt < 2; ++nt)
#pragma unroll
            for (int j = 0; j < 8; ++j)
                B2f[kt][nt][j] = (_Float16)W2[(kt*32 + q*8 + j)*32 + nt*16 + n16];

    f16x8 B3f;  // K=32, N=16: single tile
#pragma unroll
    for (int j = 0; j < 8; ++j)
        B3f[j] = (_Float16)W3[(q*8 + j)*16 + n16];

    const float bias2_0 = b2[n16];
    const float bias2_1 = b2[16 + n16];
    const float bias3   = b3[n16];

    // ---- load input row ----
    float x[6];
    {
        const float* mp = margins + (size_t)rowC * 6;
#pragma unroll
        for (int i = 0; i < 6; ++i) x[i] = mp[i];
    }

    // ---- scalar layer 1 (fp32; W1 rows contiguous -> s_load_dwordx16) ----
    float h1[64];
#pragma unroll
    for (int k = 0; k < 64; ++k) h1[k] = b1[k];
#pragma unroll
    for (int i = 0; i < 6; ++i) {
        const float xi = x[i];
        const float* w = W1 + i * 64;
#pragma unroll
        for (int k = 0; k < 64; ++k) h1[k] = fmaf(xi, w[k], h1[k]);
    }

    // ---- relu + f16 pack + write H1 row (stride 144 B, 16B-aligned) ----
    {
        char* rp = smem + lane * 144;
#pragma unroll
        for (int i = 0; i < 8; ++i) {
            f16x8 hv;
#pragma unroll
            for (int j = 0; j < 8; ++j)
                hv[j] = (_Float16)fmaxf(h1[8*i + j], 0.0f);
            *(f16x8*)(rp + i * 16) = hv;
        }
    }

    // ---- pre-read ALL A2 fragments (full H1) into VGPRs ----
    // A layout (m89-verified): A[m=lane&15][k=q*8+j], 8 contiguous f16 -> b128
    f16x8 A2[4][2];
#pragma unroll
    for (int mt = 0; mt < 4; ++mt)
#pragma unroll
        for (int kt = 0; kt < 2; ++kt)
            A2[mt][kt] = *(const f16x8*)(smem + (mt*16 + n16)*144 + kt*64 + q*16);

    // ---- MFMA layer 2: 64x64 @ 64x32, bias in C operand, relu on store ----
    // C layout: col = lane&15, row = q*4 + reg  (dtype-independent, m89/m121)
#pragma unroll
    for (int mt = 0; mt < 4; ++mt) {
#pragma unroll
        for (int nt = 0; nt < 2; ++nt) {
            f32x4 C;
            const float bb = nt ? bias2_1 : bias2_0;
            C[0] = bb; C[1] = bb; C[2] = bb; C[3] = bb;
            C = __builtin_amdgcn_mfma_f32_16x16x32_f16(A2[mt][0], B2f[0][nt], C, 0, 0, 0);
            C = __builtin_amdgcn_mfma_f32_16x16x32_f16(A2[mt][1], B2f[1][nt], C, 0, 0, 0);
            const int row0 = mt*16 + q*4;
            char* base = smem + (size_t)(nt*16 + n16) * 2;
#pragma unroll
            for (int r = 0; r < 4; ++r)
                *(_Float16*)(base + (row0 + r) * 80) = (_Float16)fmaxf(C[r], 0.0f);
        }
    }

    // ---- pre-read A3 fragments (full H2) ----
    f16x8 A3[4];
#pragma unroll
    for (int mt = 0; mt < 4; ++mt)
        A3[mt] = *(const f16x8*)(smem + (mt*16 + n16)*80 + q*16);

    // ---- MFMA layer 3: 64x32 @ 32x16 -> H3 as f32 (stride 80 B) ----
#pragma unroll
    for (int mt = 0; mt < 4; ++mt) {
        f32x4 C;
        C[0] = bias3; C[1] = bias3; C[2] = bias3; C[3] = bias3;
        C = __builtin_amdgcn_mfma_f32_16x16x32_f16(A3[mt], B3f, C, 0, 0, 0);
        const int row0 = mt*16 + q*4;
#pragma unroll
        for (int r = 0; r < 4; ++r)
            *(float*)(smem + (row0 + r) * 80 + n16 * 4) = fmaxf(C[r], 0.0f);
    }

    // ---- each lane reads its own h3 row (4 x b128, 16B-aligned) ----
    float h3[16];
    {
        const char* rp = smem + lane * 80;
#pragma unroll
        for (int i = 0; i < 4; ++i)
            *(f32x4*)&h3[4*i] = *(const f32x4*)(rp + i * 16);
    }

    // ---- scalar layer 4: 16 -> 9 (W4 rows contiguous -> scalar loads) ----
    float p[9];
#pragma unroll
    for (int k = 0; k < 9; ++k) p[k] = b4[k];
#pragma unroll
    for (int j = 0; j < 16; ++j) {
        const float hj = h3[j];
        const float* w = W4 + j * 9;
#pragma unroll
        for (int k = 0; k < 9; ++k) p[k] = fmaf(hj, w[k], p[k]);
    }

    // ---- heads ----
    float A00 = __expf(p[0]), A01 = __expf(p[1]);
    float A10 = __expf(p[2]), A11 = __expf(p[3]);
    float A02 = 1.0f, A12 = 1.0f, A20 = 1.0f, A21 = 1.0f, A22 = 1.0f;

    const float sh_m0 = kLOW + (kHIGH - kLOW) * fast_sigmoid(p[4]);
    const float sh_m1 = kLOW + (kHIGH - kLOW) * fast_sigmoid(p[5]);
    const float sh_f0 = kLOW + (kHIGH - kLOW) * fast_sigmoid(p[6]);
    const float sh_f1 = kLOW + (kHIGH - kLOW) * fast_sigmoid(p[7]);
    const float V = __expf(p[8]);

    const float M0 = x[0], M1 = x[1], M2 = x[2];
    const float F0 = x[3], F1 = x[4], F2 = x[5];

    const float r0 = M0 * sh_m0, r1 = M1 * sh_m1, r2 = M2;
    const float c0 = F0 * sh_f0, c1 = F1 * sh_f1, c2 = F2;
    const float mum0_0 = M0 * (1.0f - sh_m0), mum0_1 = M1 * (1.0f - sh_m1);
    const float mu0f_0 = F0 * (1.0f - sh_f0), mu0f_1 = F1 * (1.0f - sh_f1);

    // ---- Sinkhorn-Knopp, 10 iterations, in registers ----
#pragma unroll
    for (int it = 0; it < 10; ++it) {
        float s0 = A00 + A01 + A02;
        float s1 = A10 + A11 + A12;
        float s2 = A20 + A21 + A22;
        float f0 = __fdividef(r0, s0 + kEPS);
        float f1 = __fdividef(r1, s1 + kEPS);
        float f2 = __fdividef(r2, s2 + kEPS);
        A00 *= f0; A01 *= f0; A02 *= f0;
        A10 *= f1; A11 *= f1; A12 *= f1;
        A20 *= f2; A21 *= f2; A22 *= f2;
        float t0 = A00 + A10 + A20;
        float t1 = A01 + A11 + A21;
        float t2 = A02 + A12 + A22;
        float g0 = __fdividef(c0, t0 + kEPS);
        float g1 = __fdividef(c1, t1 + kEPS);
        float g2 = __fdividef(c2, t2 + kEPS);
        A00 *= g0; A10 *= g0; A20 *= g0;
        A01 *= g1; A11 *= g1; A21 *= g1;
        A02 *= g2; A12 *= g2; A22 *= g2;
    }

    // ---- store ----
    if (row < B) {
        float4* o = (float4*)(out_mus + (size_t)row * 16);
        o[0] = make_float4(A00, A01, A02, mum0_0);
        o[1] = make_float4(A10, A11, A12, mum0_1);
        o[2] = make_float4(A20, A21, A22, 0.0f);
        o[3] = make_float4(mu0f_0, mu0f_1, 0.0f, 0.0f);
        out_V[row] = V;
    }
}

extern "C" void kernel_launch(void* const* d_in, const int* in_sizes, int n_in,
                              void* d_out, int out_size, void* d_ws, size_t ws_size,
                              hipStream_t stream) {
    const float* margins = (const float*)d_in[0];
    const float* W1 = (const float*)d_in[1];
    const float* b1 = (const float*)d_in[2];
    const float* W2 = (const float*)d_in[3];
    const float* b2 = (const float*)d_in[4];
    const float* W3 = (const float*)d_in[5];
    const float* b3 = (const float*)d_in[6];
    const float* W4 = (const float*)d_in[7];
    const float* b4 = (const float*)d_in[8];

    const int B = in_sizes[0] / 6;
    float* out_mus = (float*)d_out;
    float* out_V   = out_mus + (size_t)B * 16;

    dim3 block(256);
    dim3 grid((B + 255) / 256);
    hipLaunchKernelGGL(sinkhorn_mlp_mfma, grid, block, 0, stream,
                       margins, W1, b1, W2, b2, W3, b3, W4, b4,
                       out_mus, out_V, B);
}

// Round 4
// 229.916 us; speedup vs baseline: 1.5529x; 1.0904x over previous
//
#include <hip/hip_runtime.h>

typedef _Float16 f16x8 __attribute__((ext_vector_type(8)));
typedef float    f32x4 __attribute__((ext_vector_type(4)));

static constexpr float kLOW  = 0.02f;
static constexpr float kHIGH = 0.98f;

__device__ __forceinline__ float fast_sigmoid(float v) {
    return 1.0f / (1.0f + __expf(-v));
}
__device__ __forceinline__ float fast_rcp(float v) {
    return __builtin_amdgcn_rcpf(v);  // v_rcp_f32, ~1e-7 rel err
}

// Per-wave layout: 64 rows/wave, waves independent (no barriers).
// LDS slice per wave: 9216 B, reused: H1 (f16, 64 x stride 144B)
//   -> H2 (f16, stride 80B) -> H3 (f32, stride 80B).
// All A-fragments pre-read to VGPRs before the aliasing writes.
// __launch_bounds__(256,4): LDS (36.9KB) caps at 4 blocks/CU anyway; ask for
// exactly 4 waves/EU -> 128-VGPR budget. R3 had VGPR_Count=56 + AGPR spill
// shuffle on h1[64]; layer 1 is now chunked (8 live accs) so nothing forces
// a big live array.
__global__ __launch_bounds__(256, 4) void sinkhorn_mlp_mfma(
    const float* __restrict__ margins,
    const float* __restrict__ W1, const float* __restrict__ b1,
    const float* __restrict__ W2, const float* __restrict__ b2,
    const float* __restrict__ W3, const float* __restrict__ b3,
    const float* __restrict__ W4, const float* __restrict__ b4,
    float* __restrict__ out_mus, float* __restrict__ out_V, int B)
{
    __shared__ __align__(16) char smem_all[4 * 9216];
    const int lane = threadIdx.x & 63;
    const int wid  = threadIdx.x >> 6;
    char* smem = smem_all + wid * 9216;

    const int n16 = lane & 15;   // MFMA col / m index
    const int q   = lane >> 4;   // quad 0..3

    const int row  = blockIdx.x * 256 + wid * 64 + lane;
    const int rowC = row < B ? row : (B - 1);

    // ---- B-fragments (weights, wave-invariant) into VGPRs, f16 ----
    f16x8 B2f[2][2];  // [kt][nt]  K=64 -> 2 k-tiles, N=32 -> 2 n-tiles
#pragma unroll
    for (int kt = 0; kt < 2; ++kt)
#pragma unroll
        for (int nt = 0; nt < 2; ++nt)
#pragma unroll
            for (int j = 0; j < 8; ++j)
                B2f[kt][nt][j] = (_Float16)W2[(kt*32 + q*8 + j)*32 + nt*16 + n16];

    f16x8 B3f;  // K=32, N=16: single tile
#pragma unroll
    for (int j = 0; j < 8; ++j)
        B3f[j] = (_Float16)W3[(q*8 + j)*16 + n16];

    const float bias2_0 = b2[n16];
    const float bias2_1 = b2[16 + n16];
    const float bias3   = b3[n16];

    // ---- load input row ----
    float x[6];
    {
        const float* mp = margins + (size_t)rowC * 6;
#pragma unroll
        for (int i = 0; i < 6; ++i) x[i] = mp[i];
    }

    // ---- scalar layer 1, CHUNKED: 8 accumulators at a time ----
    // bias folded into first fma; relu+pack+store per chunk -> live set ~8.
    {
        char* rp = smem + lane * 144;
#pragma unroll
        for (int c = 0; c < 8; ++c) {
            f16x8 hv;
#pragma unroll
            for (int k = 0; k < 8; ++k) {
                const int col = c * 8 + k;
                float a = fmaf(x[0], W1[col], b1[col]);
#pragma unroll
                for (int i = 1; i < 6; ++i) a = fmaf(x[i], W1[i * 64 + col], a);
                hv[k] = (_Float16)fmaxf(a, 0.0f);
            }
            *(f16x8*)(rp + c * 16) = hv;
        }
    }

    // ---- pre-read ALL A2 fragments (full H1) into VGPRs ----
    f16x8 A2[4][2];
#pragma unroll
    for (int mt = 0; mt < 4; ++mt)
#pragma unroll
        for (int kt = 0; kt < 2; ++kt)
            A2[mt][kt] = *(const f16x8*)(smem + (mt*16 + n16)*144 + kt*64 + q*16);

    // ---- MFMA layer 2: 64x64 @ 64x32, bias in C, relu on store ----
#pragma unroll
    for (int mt = 0; mt < 4; ++mt) {
#pragma unroll
        for (int nt = 0; nt < 2; ++nt) {
            f32x4 C;
            const float bb = nt ? bias2_1 : bias2_0;
            C[0] = bb; C[1] = bb; C[2] = bb; C[3] = bb;
            C = __builtin_amdgcn_mfma_f32_16x16x32_f16(A2[mt][0], B2f[0][nt], C, 0, 0, 0);
            C = __builtin_amdgcn_mfma_f32_16x16x32_f16(A2[mt][1], B2f[1][nt], C, 0, 0, 0);
            const int row0 = mt*16 + q*4;
            char* base = smem + (size_t)(nt*16 + n16) * 2;
#pragma unroll
            for (int r = 0; r < 4; ++r)
                *(_Float16*)(base + (row0 + r) * 80) = (_Float16)fmaxf(C[r], 0.0f);
        }
    }

    // ---- pre-read A3 fragments (full H2) ----
    f16x8 A3[4];
#pragma unroll
    for (int mt = 0; mt < 4; ++mt)
        A3[mt] = *(const f16x8*)(smem + (mt*16 + n16)*80 + q*16);

    // ---- MFMA layer 3: 64x32 @ 32x16 -> H3 as f32 (relu folded in store) ----
#pragma unroll
    for (int mt = 0; mt < 4; ++mt) {
        f32x4 C;
        C[0] = bias3; C[1] = bias3; C[2] = bias3; C[3] = bias3;
        C = __builtin_amdgcn_mfma_f32_16x16x32_f16(A3[mt], B3f, C, 0, 0, 0);
        const int row0 = mt*16 + q*4;
#pragma unroll
        for (int r = 0; r < 4; ++r)
            *(float*)(smem + (row0 + r) * 80 + n16 * 4) = fmaxf(C[r], 0.0f);
    }

    // ---- each lane reads its own h3 row ----
    float h3[16];
    {
        const char* rp = smem + lane * 80;
#pragma unroll
        for (int i = 0; i < 4; ++i)
            *(f32x4*)&h3[4*i] = *(const f32x4*)(rp + i * 16);
    }

    // ---- scalar layer 4: 16 -> 9 ----
    float p[9];
#pragma unroll
    for (int k = 0; k < 9; ++k) p[k] = fmaf(h3[0], W4[k], b4[k]);
#pragma unroll
    for (int j = 1; j < 16; ++j) {
        const float hj = h3[j];
        const float* w = W4 + j * 9;
#pragma unroll
        for (int k = 0; k < 9; ++k) p[k] = fmaf(hj, w[k], p[k]);
    }

    // ---- heads ----
    const float K00 = __expf(p[0]), K01 = __expf(p[1]);
    const float K10 = __expf(p[2]), K11 = __expf(p[3]);

    const float sh_m0 = kLOW + (kHIGH - kLOW) * fast_sigmoid(p[4]);
    const float sh_m1 = kLOW + (kHIGH - kLOW) * fast_sigmoid(p[5]);
    const float sh_f0 = kLOW + (kHIGH - kLOW) * fast_sigmoid(p[6]);
    const float sh_f1 = kLOW + (kHIGH - kLOW) * fast_sigmoid(p[7]);
    const float V = __expf(p[8]);

    const float M0 = x[0], M1 = x[1], M2 = x[2];
    const float F0 = x[3], F1 = x[4], F2 = x[5];

    const float r0 = M0 * sh_m0, r1 = M1 * sh_m1, r2 = M2;
    const float c0 = F0 * sh_f0, c1 = F1 * sh_f1, c2 = F2;
    const float mum0_0 = M0 * (1.0f - sh_m0), mum0_1 = M1 * (1.0f - sh_m1);
    const float mu0f_0 = F0 * (1.0f - sh_f0), mu0f_1 = F1 * (1.0f - sh_f1);

    // ---- Sinkhorn-Knopp in u/v scaling form over fixed kernel K ----
    // K = [[K00,K01,1],[K10,K11,1],[1,1,1]]; A = diag(u) K diag(v).
    // Row step: u_i = r_i / (K v)_i ; col step: v_j = c_j / (K^T u)_j.
    // eps=1e-12 dropped: all quantities are positive O(0.01..10); eps shifts
    // results ~1e-11 rel, 9 orders below the 2e-2 output budget.
    float u0, u1, u2;
    float v0 = 1.0f, v1 = 1.0f, v2 = 1.0f;
#pragma unroll
    for (int it = 0; it < 10; ++it) {
        const float s0 = fmaf(K00, v0, fmaf(K01, v1, v2));
        const float s1 = fmaf(K10, v0, fmaf(K11, v1, v2));
        const float s2 = v0 + v1 + v2;
        u0 = r0 * fast_rcp(s0);
        u1 = r1 * fast_rcp(s1);
        u2 = r2 * fast_rcp(s2);
        const float t0 = fmaf(K00, u0, fmaf(K10, u1, u2));
        const float t1 = fmaf(K01, u0, fmaf(K11, u1, u2));
        const float t2 = u0 + u1 + u2;
        v0 = c0 * fast_rcp(t0);
        v1 = c1 * fast_rcp(t1);
        v2 = c2 * fast_rcp(t2);
    }
    const float A00 = u0 * K00 * v0, A01 = u0 * K01 * v1, A02 = u0 * v2;
    const float A10 = u1 * K10 * v0, A11 = u1 * K11 * v1, A12 = u1 * v2;
    const float A20 = u2 * v0,       A21 = u2 * v1,       A22 = u2 * v2;

    // ---- store ----
    if (row < B) {
        float4* o = (float4*)(out_mus + (size_t)row * 16);
        o[0] = make_float4(A00, A01, A02, mum0_0);
        o[1] = make_float4(A10, A11, A12, mum0_1);
        o[2] = make_float4(A20, A21, A22, 0.0f);
        o[3] = make_float4(mu0f_0, mu0f_1, 0.0f, 0.0f);
        out_V[row] = V;
    }
}

extern "C" void kernel_launch(void* const* d_in, const int* in_sizes, int n_in,
                              void* d_out, int out_size, void* d_ws, size_t ws_size,
                              hipStream_t stream) {
    const float* margins = (const float*)d_in[0];
    const float* W1 = (const float*)d_in[1];
    const float* b1 = (const float*)d_in[2];
    const float* W2 = (const float*)d_in[3];
    const float* b2 = (const float*)d_in[4];
    const float* W3 = (const float*)d_in[5];
    const float* b3 = (const float*)d_in[6];
    const float* W4 = (const float*)d_in[7];
    const float* b4 = (const float*)d_in[8];

    const int B = in_sizes[0] / 6;
    float* out_mus = (float*)d_out;
    float* out_V   = out_mus + (size_t)B * 16;

    dim3 block(256);
    dim3 grid((B + 255) / 256);
    hipLaunchKernelGGL(sinkhorn_mlp_mfma, grid, block, 0, stream,
                       margins, W1, b1, W2, b2, W3, b3, W4, b4,
                       out_mus, out_V, B);
}